// Round 10
// baseline (190.485 us; speedup 1.0000x reference)
//
#include <hip/hip_runtime.h>
#include <math.h>

// Problem constants (fixed by the reference).
#define NITEMS 50000
#define BATCH  512
#define LLEN   50
#define KTOP   20
#define HDIM   32
#define DDIM   32
#define NCH    5
#define NSEG   33             // H+1 piecewise-linear segments
#define NSCAL  200            // scalars per item
#define NCELL  100            // (c,k) cells
#define THRP   33             // padded LDS stride for sorted thresholds
#define NWAVE  8              // waves per block
#define CSLOT  13             // ceil(100/8) cells per 8-lane group

typedef _Float16 h2 __attribute__((ext_vector_type(2)));

static __device__ __forceinline__ float dot2_acc(h2 a, h2 b, float c) {
#if __has_builtin(__builtin_amdgcn_fdot2)
    return __builtin_amdgcn_fdot2(a, b, c, false);
#else
    return fmaf((float)a.x, (float)b.x, fmaf((float)a.y, (float)b.y, c));
#endif
}

// ws layout (floats):
//   [0, 160)       sorted thr[c][0..31] (ascending per channel)
//   [160, 5440)    AB16 table: 5280 uints, fp16 swizzled (see below)
//   [5440, 5952)   row order (ints) from the length sort
#define WS_THRS  0
#define WS_AB16  160
#define WS_ORDER 5440

// fp16 table layout: row (c,s) = 32 uints (128 B).  Chunk d4 (0..7) = 4
// uints: [A(4d4,4d4+1), B(4d4,4d4+1), A(4d4+2,4d4+3), B(4d4+2,4d4+3)]
// where A(a,b) packs halves (lo=A_a, hi=A_b).  A lane's b128 read of its
// chunk is directly v_pk_fma_f16-ready.

// ---------------------------------------------------------------------------
// Setup + sort, one dispatch. Blocks 0..32: affine coeffs of the scalar MLP
// per (channel, segment); block 0 also writes the per-channel SORTED
// thresholds.  Block 33: COUNTING sort of the 512 lens (R10: lens in [1,50];
// 4 barriers vs bitonic's 45).  Within-bin order nondeterministic -- perf-
// only permutation, any order is correct.
// ---------------------------------------------------------------------------
__global__ __launch_bounds__(256) void cnn_setup(
        const float* __restrict__ W1, const float* __restrict__ b1,
        const float* __restrict__ W2, const float* __restrict__ b2,
        const int* __restrict__ user_lens,
        float* __restrict__ ws, int* __restrict__ order) {
    const int tid = threadIdx.x;

    if (blockIdx.x < NSEG) {
        __shared__ float sW1[NCH*HDIM], sB1[NCH*HDIM], sThr[NCH*HDIM];
        __shared__ int   sRank[NCH*HDIM];
        __shared__ float sW2[NCH*HDIM*DDIM];     // 20 KB
        __shared__ float sB2[NCH*DDIM];

        for (int i = tid; i < NCH*HDIM; i += 256) { sW1[i] = W1[i]; sB1[i] = b1[i]; }
        for (int i = tid; i < NCH*HDIM*DDIM; i += 256) sW2[i] = W2[i];
        for (int i = tid; i < NCH*DDIM; i += 256) sB2[i] = b2[i];
        __syncthreads();

        for (int i = tid; i < NCH*HDIM; i += 256) {
            float w = sW1[i];
            sThr[i] = (w != 0.f) ? (-sB1[i] / w) : INFINITY;
        }
        __syncthreads();

        for (int i = tid; i < NCH*HDIM; i += 256) {
            int c = i / HDIM, h = i % HDIM;
            float thr = sThr[i];
            int rank = 0;
            for (int h2i = 0; h2i < HDIM; ++h2i) {
                float thr2 = sThr[c*HDIM + h2i];
                rank += (thr2 < thr || (thr2 == thr && h2i < h)) ? 1 : 0;
            }
            sRank[i] = rank;
            if (blockIdx.x == 0) ws[WS_THRS + c*HDIM + rank] = thr;
        }
        __syncthreads();

        const int s = blockIdx.x;                 // segment
        if (tid < NCH*DDIM) {
            int c = tid / DDIM, d = tid % DDIM;
            float A = 0.f, Bv = 0.f;
#pragma unroll
            for (int h = 0; h < HDIM; ++h) {
                float w  = sW1[c*HDIM + h];
                float bb = sB1[c*HDIM + h];
                int   r  = sRank[c*HDIM + h];
                bool active = (w > 0.f) ? (r < s) : ((w < 0.f) ? (r >= s) : (bb > 0.f));
                if (active) {
                    float w2 = sW2[(c*HDIM + h)*DDIM + d];
                    A  = fmaf(w,  w2, A);
                    Bv = fmaf(bb, w2, Bv);
                }
            }
            Bv += sB2[c*DDIM + d];
            unsigned short* ab = (unsigned short*)(ws + WS_AB16);
            int d4 = d >> 2, dd = d & 3;
            int base = ((c*NSEG + s)*32 + d4*4)*2;          // ushort index
            _Float16 ah = (_Float16)A, bh = (_Float16)Bv;
            ab[base + 4*(dd>>1) + (dd&1)]     = __builtin_bit_cast(unsigned short, ah);
            ab[base + 4*(dd>>1) + 2 + (dd&1)] = __builtin_bit_cast(unsigned short, bh);
        }
    } else {
        // ---- counting sort of rows by len (ascending) --------------------
        __shared__ int sHist[LLEN + 1];
        for (int i = tid; i <= LLEN; i += 256) sHist[i] = 0;
        __syncthreads();
        for (int i = tid; i < BATCH; i += 256) atomicAdd(&sHist[user_lens[i]], 1);
        __syncthreads();
        if (tid == 0) {
            int accum = 0;
            for (int l = 1; l <= LLEN; ++l) { int c = sHist[l]; sHist[l] = accum; accum += c; }
        }
        __syncthreads();
        for (int i = tid; i < BATCH; i += 256) {
            int pos = atomicAdd(&sHist[user_lens[i]], 1);
            order[pos] = i;
        }
    }
}

// ---------------------------------------------------------------------------
// Main (R10): R9 + 2-deep software pipeline in the stripe loop.
// R9 post-mortem: main ~19us vs ~13us LDS-issue floor -- the gap is the
// intra-item serial chain (C(j) reads the sxo words S(j) just wrote, paying
// the 5-deep binary-search LDS latency every item).  R10: double-buffered
// sxo; iteration = C(j) from buf j&1, then S(j+1) into buf (j+1)&1 -- C
// depends only on last iteration's writes, S(j+1)'s latency chain overlaps
// C(j)'s read stream.  Same math, same order, exact.
// ---------------------------------------------------------------------------
__global__ __launch_bounds__(512, 4) void cnn_main(
        const float* __restrict__ ctx,  const float* __restrict__ ws,
        const float* __restrict__ Wout, const float* __restrict__ bout,
        const int* __restrict__ item_idxs, const int* __restrict__ user_items,
        const int* __restrict__ user_lens, const int* __restrict__ order,
        float* __restrict__ out) {
    __shared__ unsigned int sAB16[NCH*NSEG*32];  // 21120 B, swizzled fp16
    __shared__ float  sThrS[NCH*THRP];           // sorted thr, stride 33
    __shared__ uint2  sxo[NWAVE][2][NCELL];      // double-buffered per wave
    __shared__ uint2  sWt[NCELL*8];              // [cell*8+d4] target wt bits
    __shared__ float  pRed[NWAVE][NCELL];        // per-wave scalar partials

    const int tid  = threadIdx.x;
    const int w    = tid >> 6;              // wave 0..7
    const int lane = tid & 63;
    const int g    = lane >> 3;             // cell sub-group 0..7
    const int d4   = lane & 7;              // covers d = 4*d4 .. 4*d4+3

    // Stage fp16 table + sorted thresholds.
    const uint4* ABg = reinterpret_cast<const uint4*>(ws + WS_AB16);
    uint4* sAB4 = reinterpret_cast<uint4*>(sAB16);
    for (int i = tid; i < NCH*NSEG*8; i += 512) sAB4[i] = ABg[i];
    for (int i = tid; i < NCH*THRP; i += 512) {
        int c = i / THRP, j = i - c*THRP;
        sThrS[i] = (j < HDIM) ? ws[WS_THRS + c*HDIM + j] : 0.f;
    }

    // Sorted pairing (ranks r and 511-r co-resident under round-robin).
    const int rank = (blockIdx.x < 256) ? blockIdx.x : (767 - blockIdx.x);
    const int b    = order[rank];
    const int len  = user_lens[b];          // >= 1
    const float inv_len = 1.f / (float)len;
    const float bo = bout[0];
    const h2 wv0 = {(_Float16)Wout[4*d4],     (_Float16)Wout[4*d4 + 1]};
    const h2 wv1 = {(_Float16)Wout[4*d4 + 2], (_Float16)Wout[4*d4 + 3]};

    // Per-(lane,round) phase-S constants (fixed across items).
    int sc[4], sdst[4];
#pragma unroll
    for (int r = 0; r < 4; ++r) {
        int idx  = lane + 64*r;
        int c    = idx / 40, rr = idx - c*40;
        int cell = c*KTOP + (rr % KTOP);
        sc[r]   = c;
        sdst[r] = cell*8 + (rr / KTOP)*4;   // byte offset within a buffer
    }

    const int nstripe = (len > w) ? ((len - w + NWAVE - 1) / NWAVE) : 0;

    unsigned int wtA[CSLOT], wtB[CSLOT];    // target rep * Wout (h2 bits)
    float acc[CSLOT];
#pragma unroll
    for (int i = 0; i < CSLOT; ++i) acc[i] = 0.f;

    char* sxoB = (char*)&sxo[w][0][0];      // buf k at +k*800 bytes

    __syncthreads();                        // staging visible to all waves

    // Prefetch this wave's first stripe item (overlaps wave 0's target).
    float xp[4] = {0.f, 0.f, 0.f, 0.f};
    if (nstripe > 0) {
        const float* row = ctx + (size_t)user_items[b*LLEN + w] * NSCAL;
#pragma unroll
        for (int r = 0; r < 4; ++r) {
            int idx = lane + 64*r;
            if (idx < NSCAL) xp[r] = row[idx];
        }
    }

    // ======== target item: wave 0 only, broadcast via sWt ================
    if (w == 0) {
        float xt[4] = {0.f, 0.f, 0.f, 0.f};
        const float* row = ctx + (size_t)item_idxs[b] * NSCAL;
#pragma unroll
        for (int r = 0; r < 4; ++r) {
            int idx = lane + 64*r;
            if (idx < NSCAL) xt[r] = row[idx];
        }
#pragma unroll
        for (int r = 0; r < 4; ++r) {
            int idx = lane + 64*r;
            if (idx < NSCAL) {
                float xv = xt[r];
                int base = sc[r]*THRP;
                int pos = 0;
                pos += (sThrS[base + pos + 15] < xv) ? 16 : 0;
                pos += (sThrS[base + pos + 7]  < xv) ? 8  : 0;
                pos += (sThrS[base + pos + 3]  < xv) ? 4  : 0;
                pos += (sThrS[base + pos + 1]  < xv) ? 2  : 0;
                pos += (sThrS[base + pos]      < xv) ? 1  : 0;
                unsigned int off = (unsigned int)((sc[r]*NSEG + pos) << 7);
                _Float16 xh = (_Float16)xv;
                unsigned int word = (unsigned int)__builtin_bit_cast(unsigned short, xh)
                                  | (off << 16);
                *(unsigned int*)(sxoB + sdst[r]) = word;   // buf 0
            }
        }
        __builtin_amdgcn_wave_barrier();
#pragma unroll
        for (int i = 0; i < CSLOT; ++i) {
            int cell = g + 8*i;
            if (cell < NCELL) {
                uint2 xo = sxo[0][0][cell];
                const uint4* p0 = (const uint4*)((const char*)sAB16 + (xo.x >> 16) + (d4 << 4));
                const uint4* p1 = (const uint4*)((const char*)sAB16 + (xo.y >> 16) + (d4 << 4));
                uint4 q0 = *p0, q1 = *p1;
                _Float16 x0h = __builtin_bit_cast(_Float16, (unsigned short)(xo.x & 0xffffu));
                _Float16 x1h = __builtin_bit_cast(_Float16, (unsigned short)(xo.y & 0xffffu));
                h2 x0 = {x0h, x0h}, x1 = {x1h, x1h};
                h2 repa = (x0 * __builtin_bit_cast(h2, q0.x) + __builtin_bit_cast(h2, q0.y))
                        * (x1 * __builtin_bit_cast(h2, q1.x) + __builtin_bit_cast(h2, q1.y));
                h2 repb = (x0 * __builtin_bit_cast(h2, q0.z) + __builtin_bit_cast(h2, q0.w))
                        * (x1 * __builtin_bit_cast(h2, q1.z) + __builtin_bit_cast(h2, q1.w));
                wtA[i] = __builtin_bit_cast(unsigned int, (h2)(repa * wv0));
                wtB[i] = __builtin_bit_cast(unsigned int, (h2)(repb * wv1));
                sWt[cell*8 + d4] = make_uint2(wtA[i], wtB[i]);
            }
        }
    }
    __syncthreads();                        // sWt ready for all waves

    if (w != 0) {
#pragma unroll
        for (int i = 0; i < CSLOT; ++i) {
            int cell = g + 8*i;
            if (cell < NCELL) {
                uint2 v = sWt[cell*8 + d4];
                wtA[i] = v.x; wtB[i] = v.y;
            }
        }
    }

    // ======== stripe items: 2-deep pipeline, no per-item barriers ========
    // S(0) into buf 0; then per iteration: C(j) from buf j&1, S(j+1) into
    // buf (j+1)&1, prefetch x for j+2.  Same-wave LDS ops are in-order;
    // wave_barrier pins compiler ordering at iteration edges.
    if (nstripe > 0) {
#pragma unroll
        for (int r = 0; r < 4; ++r) {
            int idx = lane + 64*r;
            if (idx < NSCAL) {
                float xv = xp[r];
                int base = sc[r]*THRP;
                int pos = 0;
                pos += (sThrS[base + pos + 15] < xv) ? 16 : 0;
                pos += (sThrS[base + pos + 7]  < xv) ? 8  : 0;
                pos += (sThrS[base + pos + 3]  < xv) ? 4  : 0;
                pos += (sThrS[base + pos + 1]  < xv) ? 2  : 0;
                pos += (sThrS[base + pos]      < xv) ? 1  : 0;
                unsigned int off = (unsigned int)((sc[r]*NSEG + pos) << 7);
                _Float16 xh = (_Float16)xv;
                unsigned int word = (unsigned int)__builtin_bit_cast(unsigned short, xh)
                                  | (off << 16);
                *(unsigned int*)(sxoB + sdst[r]) = word;   // buf 0
            }
        }
        if (nstripe > 1) {
            const float* row = ctx + (size_t)user_items[b*LLEN + w + NWAVE] * NSCAL;
#pragma unroll
            for (int r = 0; r < 4; ++r) {
                int idx = lane + 64*r;
                if (idx < NSCAL) xp[r] = row[idx];
            }
        }
    }

    for (int j = 0; j < nstripe; ++j) {
        __builtin_amdgcn_wave_barrier();

        // ---- phase C(j): reads buf j&1 (written last iteration) ---------
        const uint2* bufC = &sxo[w][j & 1][0];
#pragma unroll
        for (int i = 0; i < CSLOT; ++i) {
            int cell = g + 8*i;
            if (cell < NCELL) {
                uint2 xo = bufC[cell];
                const uint4* p0 = (const uint4*)((const char*)sAB16 + (xo.x >> 16) + (d4 << 4));
                const uint4* p1 = (const uint4*)((const char*)sAB16 + (xo.y >> 16) + (d4 << 4));
                uint4 q0 = *p0, q1 = *p1;
                _Float16 x0h = __builtin_bit_cast(_Float16, (unsigned short)(xo.x & 0xffffu));
                _Float16 x1h = __builtin_bit_cast(_Float16, (unsigned short)(xo.y & 0xffffu));
                h2 x0 = {x0h, x0h}, x1 = {x1h, x1h};
                h2 repa = (x0 * __builtin_bit_cast(h2, q0.x) + __builtin_bit_cast(h2, q0.y))
                        * (x1 * __builtin_bit_cast(h2, q1.x) + __builtin_bit_cast(h2, q1.y));
                h2 repb = (x0 * __builtin_bit_cast(h2, q0.z) + __builtin_bit_cast(h2, q0.w))
                        * (x1 * __builtin_bit_cast(h2, q1.z) + __builtin_bit_cast(h2, q1.w));
                acc[i] = dot2_acc(repa, __builtin_bit_cast(h2, wtA[i]),
                         dot2_acc(repb, __builtin_bit_cast(h2, wtB[i]), acc[i]));
            }
        }

        // ---- phase S(j+1): writes buf (j+1)&1; overlaps C(j) ------------
        if (j + 1 < nstripe) {
            int bofs = ((j + 1) & 1) * (NCELL * 8);
#pragma unroll
            for (int r = 0; r < 4; ++r) {
                int idx = lane + 64*r;
                if (idx < NSCAL) {
                    float xv = xp[r];
                    int base = sc[r]*THRP;
                    int pos = 0;
                    pos += (sThrS[base + pos + 15] < xv) ? 16 : 0;
                    pos += (sThrS[base + pos + 7]  < xv) ? 8  : 0;
                    pos += (sThrS[base + pos + 3]  < xv) ? 4  : 0;
                    pos += (sThrS[base + pos + 1]  < xv) ? 2  : 0;
                    pos += (sThrS[base + pos]      < xv) ? 1  : 0;
                    unsigned int off = (unsigned int)((sc[r]*NSEG + pos) << 7);
                    _Float16 xh = (_Float16)xv;
                    unsigned int word = (unsigned int)__builtin_bit_cast(unsigned short, xh)
                                      | (off << 16);
                    *(unsigned int*)(sxoB + bofs + sdst[r]) = word;
                }
            }
            // prefetch x for item j+2
            if (j + 2 < nstripe) {
                const float* row = ctx + (size_t)user_items[b*LLEN + w + NWAVE*(j+2)] * NSCAL;
#pragma unroll
                for (int r = 0; r < 4; ++r) {
                    int idx = lane + 64*r;
                    if (idx < NSCAL) xp[r] = row[idx];
                }
            }
        }
        __builtin_amdgcn_wave_barrier();
    }

    // ---- epilogue: 8-lane reduce, cross-wave combine, sigmoid -----------
#pragma unroll
    for (int i = 0; i < CSLOT; ++i) {
        int cell = g + 8*i;
        float v = acc[i];
        v += __shfl_xor(v, 1, 64);
        v += __shfl_xor(v, 2, 64);
        v += __shfl_xor(v, 4, 64);
        if (d4 == 0 && cell < NCELL) pRed[w][cell] = v;
    }
    __syncthreads();
    if (tid < NCELL) {
        float p = 0.f;
#pragma unroll
        for (int q = 0; q < NWAVE; ++q) p += pRed[q][tid];
        out[b*NCELL + tid] = 1.f / (1.f + expf(-(p*inv_len + bo)));
    }
}

extern "C" void kernel_launch(void* const* d_in, const int* in_sizes, int n_in,
                              void* d_out, int out_size, void* d_ws, size_t ws_size,
                              hipStream_t stream) {
    const float* ctx   = (const float*)d_in[0];
    const float* W1    = (const float*)d_in[1];
    const float* b1    = (const float*)d_in[2];
    const float* W2    = (const float*)d_in[3];
    const float* b2    = (const float*)d_in[4];
    const float* Wout  = (const float*)d_in[5];
    const float* bout  = (const float*)d_in[6];
    const int* item_idxs  = (const int*)d_in[7];
    const int* user_items = (const int*)d_in[8];
    const int* user_lens  = (const int*)d_in[9];
    float* out = (float*)d_out;
    float* ws  = (float*)d_ws;                 // uses 23,808 B
    int*   order = (int*)(ws + WS_ORDER);

    cnn_setup<<<NSEG + 1, 256, 0, stream>>>(W1, b1, W2, b2, user_lens, ws, order);
    cnn_main<<<BATCH, 512, 0, stream>>>(ctx, ws, Wout, bout,
                                        item_idxs, user_items, user_lens,
                                        order, out);
}

// Round 11
// 114.375 us; speedup vs baseline: 1.6654x; 1.6654x over previous
//
#include <hip/hip_runtime.h>
#include <math.h>

// Problem constants (fixed by the reference).
#define NITEMS 50000
#define BATCH  512
#define LLEN   50
#define KTOP   20
#define HDIM   32
#define DDIM   32
#define NCH    5
#define NSEG   33             // H+1 piecewise-linear segments
#define NSCAL  200            // scalars per item
#define NCELL  100            // (c,k) cells
#define THRP   33             // padded LDS stride for sorted thresholds
#define NWAVE  8              // waves per block
#define CSLOT  13             // ceil(100/8) cells per 8-lane group

typedef _Float16 h2 __attribute__((ext_vector_type(2)));

static __device__ __forceinline__ float dot2_acc(h2 a, h2 b, float c) {
#if __has_builtin(__builtin_amdgcn_fdot2)
    return __builtin_amdgcn_fdot2(a, b, c, false);
#else
    return fmaf((float)a.x, (float)b.x, fmaf((float)a.y, (float)b.y, c));
#endif
}

// ws layout (floats):
//   [0, 160)       sorted thr[c][0..31] (ascending per channel)
//   [160, 5440)    AB16 table: 5280 uints, fp16 swizzled (see below)
//   [5440, 5952)   row order (ints) from the length sort
#define WS_THRS  0
#define WS_AB16  160
#define WS_ORDER 5440

// fp16 table layout: row (c,s) = 32 uints (128 B).  Chunk d4 (0..7) = 4
// uints: [A(4d4,4d4+1), B(4d4,4d4+1), A(4d4+2,4d4+3), B(4d4+2,4d4+3)]
// where A(a,b) packs halves (lo=A_a, hi=A_b).  A lane's b128 read of its
// chunk is directly v_pk_fma_f16-ready.

// ---------------------------------------------------------------------------
// Setup + sort, one dispatch. Blocks 0..32: affine coeffs of the scalar MLP
// per (channel, segment); block 0 also writes the per-channel SORTED
// thresholds.  Block 33: COUNTING sort of the 512 lens (lens in [1,50];
// 4 barriers).  Within-bin order nondeterministic -- perf-only permutation,
// any order is correct.
// ---------------------------------------------------------------------------
__global__ __launch_bounds__(256) void cnn_setup(
        const float* __restrict__ W1, const float* __restrict__ b1,
        const float* __restrict__ W2, const float* __restrict__ b2,
        const int* __restrict__ user_lens,
        float* __restrict__ ws, int* __restrict__ order) {
    const int tid = threadIdx.x;

    if (blockIdx.x < NSEG) {
        __shared__ float sW1[NCH*HDIM], sB1[NCH*HDIM], sThr[NCH*HDIM];
        __shared__ int   sRank[NCH*HDIM];
        __shared__ float sW2[NCH*HDIM*DDIM];     // 20 KB
        __shared__ float sB2[NCH*DDIM];

        for (int i = tid; i < NCH*HDIM; i += 256) { sW1[i] = W1[i]; sB1[i] = b1[i]; }
        for (int i = tid; i < NCH*HDIM*DDIM; i += 256) sW2[i] = W2[i];
        for (int i = tid; i < NCH*DDIM; i += 256) sB2[i] = b2[i];
        __syncthreads();

        for (int i = tid; i < NCH*HDIM; i += 256) {
            float w = sW1[i];
            sThr[i] = (w != 0.f) ? (-sB1[i] / w) : INFINITY;
        }
        __syncthreads();

        for (int i = tid; i < NCH*HDIM; i += 256) {
            int c = i / HDIM, h = i % HDIM;
            float thr = sThr[i];
            int rank = 0;
            for (int h2i = 0; h2i < HDIM; ++h2i) {
                float thr2 = sThr[c*HDIM + h2i];
                rank += (thr2 < thr || (thr2 == thr && h2i < h)) ? 1 : 0;
            }
            sRank[i] = rank;
            if (blockIdx.x == 0) ws[WS_THRS + c*HDIM + rank] = thr;
        }
        __syncthreads();

        const int s = blockIdx.x;                 // segment
        if (tid < NCH*DDIM) {
            int c = tid / DDIM, d = tid % DDIM;
            float A = 0.f, Bv = 0.f;
#pragma unroll
            for (int h = 0; h < HDIM; ++h) {
                float w  = sW1[c*HDIM + h];
                float bb = sB1[c*HDIM + h];
                int   r  = sRank[c*HDIM + h];
                bool active = (w > 0.f) ? (r < s) : ((w < 0.f) ? (r >= s) : (bb > 0.f));
                if (active) {
                    float w2 = sW2[(c*HDIM + h)*DDIM + d];
                    A  = fmaf(w,  w2, A);
                    Bv = fmaf(bb, w2, Bv);
                }
            }
            Bv += sB2[c*DDIM + d];
            unsigned short* ab = (unsigned short*)(ws + WS_AB16);
            int d4 = d >> 2, dd = d & 3;
            int base = ((c*NSEG + s)*32 + d4*4)*2;          // ushort index
            _Float16 ah = (_Float16)A, bh = (_Float16)Bv;
            ab[base + 4*(dd>>1) + (dd&1)]     = __builtin_bit_cast(unsigned short, ah);
            ab[base + 4*(dd>>1) + 2 + (dd&1)] = __builtin_bit_cast(unsigned short, bh);
        }
    } else {
        // ---- counting sort of rows by len (ascending) --------------------
        __shared__ int sHist[LLEN + 1];
        for (int i = tid; i <= LLEN; i += 256) sHist[i] = 0;
        __syncthreads();
        for (int i = tid; i < BATCH; i += 256) atomicAdd(&sHist[user_lens[i]], 1);
        __syncthreads();
        if (tid == 0) {
            int accum = 0;
            for (int l = 1; l <= LLEN; ++l) { int c = sHist[l]; sHist[l] = accum; accum += c; }
        }
        __syncthreads();
        for (int i = tid; i < BATCH; i += 256) {
            int pos = atomicAdd(&sHist[user_lens[i]], 1);
            order[pos] = i;
        }
    }
}

// ---------------------------------------------------------------------------
// Main (R11 = R9 verbatim): R10's pipeline restructure re-triggered the
// R7 scratch-spill pathology (VGPR clamp to 64, 192 MB scratch writes --
// the wt/acc arrays' AGPR residency is fragile to loop-shape changes).
// This is the proven non-spilling shape: one wave computes the target
// rep*Wout and broadcasts via sWt; stripe loop = prefetch -> S -> C with
// per-wave sxo, no per-item block barriers.  DO NOT restructure the stripe
// loop without checking WRITE_SIZE for spills.
// ---------------------------------------------------------------------------
__global__ __launch_bounds__(512, 4) void cnn_main(
        const float* __restrict__ ctx,  const float* __restrict__ ws,
        const float* __restrict__ Wout, const float* __restrict__ bout,
        const int* __restrict__ item_idxs, const int* __restrict__ user_items,
        const int* __restrict__ user_lens, const int* __restrict__ order,
        float* __restrict__ out) {
    __shared__ unsigned int sAB16[NCH*NSEG*32];  // 21120 B, swizzled fp16
    __shared__ float  sThrS[NCH*THRP];           // sorted thr, stride 33
    __shared__ uint2  sxo[NWAVE][NCELL];         // {x0h|off0<<16, x1h|off1<<16}
    __shared__ uint2  sWt[NCELL*8];              // [cell*8+d4] target wt bits
    __shared__ float  pRed[NWAVE][NCELL];        // per-wave scalar partials

    const int tid  = threadIdx.x;
    const int w    = tid >> 6;              // wave 0..7
    const int lane = tid & 63;
    const int g    = lane >> 3;             // cell sub-group 0..7
    const int d4   = lane & 7;              // covers d = 4*d4 .. 4*d4+3

    // Stage fp16 table + sorted thresholds.
    const uint4* ABg = reinterpret_cast<const uint4*>(ws + WS_AB16);
    uint4* sAB4 = reinterpret_cast<uint4*>(sAB16);
    for (int i = tid; i < NCH*NSEG*8; i += 512) sAB4[i] = ABg[i];
    for (int i = tid; i < NCH*THRP; i += 512) {
        int c = i / THRP, j = i - c*THRP;
        sThrS[i] = (j < HDIM) ? ws[WS_THRS + c*HDIM + j] : 0.f;
    }

    // Sorted pairing (ranks r and 511-r co-resident under round-robin).
    const int rank = (blockIdx.x < 256) ? blockIdx.x : (767 - blockIdx.x);
    const int b    = order[rank];
    const int len  = user_lens[b];          // >= 1
    const float inv_len = 1.f / (float)len;
    const float bo = bout[0];
    const h2 wv0 = {(_Float16)Wout[4*d4],     (_Float16)Wout[4*d4 + 1]};
    const h2 wv1 = {(_Float16)Wout[4*d4 + 2], (_Float16)Wout[4*d4 + 3]};

    // Per-(lane,round) phase-S constants (fixed across items).
    int sc[4], sdst[4];
#pragma unroll
    for (int r = 0; r < 4; ++r) {
        int idx  = lane + 64*r;
        int c    = idx / 40, rr = idx - c*40;
        int cell = c*KTOP + (rr % KTOP);
        sc[r]   = c;
        sdst[r] = cell*8 + (rr / KTOP)*4;   // byte offset in sxo[w]
    }

    const int nstripe = (len > w) ? ((len - w + NWAVE - 1) / NWAVE) : 0;

    unsigned int wtA[CSLOT], wtB[CSLOT];    // target rep * Wout (h2 bits)
    float acc[CSLOT];
#pragma unroll
    for (int i = 0; i < CSLOT; ++i) acc[i] = 0.f;

    char* sxoB = (char*)&sxo[w][0];

    __syncthreads();                        // staging visible to all waves

    // Prefetch this wave's first stripe item (overlaps wave 0's target).
    float xp[4] = {0.f, 0.f, 0.f, 0.f};
    if (nstripe > 0) {
        const float* row = ctx + (size_t)user_items[b*LLEN + w] * NSCAL;
#pragma unroll
        for (int r = 0; r < 4; ++r) {
            int idx = lane + 64*r;
            if (idx < NSCAL) xp[r] = row[idx];
        }
    }

    // ======== target item: wave 0 only, broadcast via sWt ================
    if (w == 0) {
        float xt[4] = {0.f, 0.f, 0.f, 0.f};
        const float* row = ctx + (size_t)item_idxs[b] * NSCAL;
#pragma unroll
        for (int r = 0; r < 4; ++r) {
            int idx = lane + 64*r;
            if (idx < NSCAL) xt[r] = row[idx];
        }
#pragma unroll
        for (int r = 0; r < 4; ++r) {
            int idx = lane + 64*r;
            if (idx < NSCAL) {
                float xv = xt[r];
                int base = sc[r]*THRP;
                int pos = 0;
                pos += (sThrS[base + pos + 15] < xv) ? 16 : 0;
                pos += (sThrS[base + pos + 7]  < xv) ? 8  : 0;
                pos += (sThrS[base + pos + 3]  < xv) ? 4  : 0;
                pos += (sThrS[base + pos + 1]  < xv) ? 2  : 0;
                pos += (sThrS[base + pos]      < xv) ? 1  : 0;
                unsigned int off = (unsigned int)((sc[r]*NSEG + pos) << 7);
                _Float16 xh = (_Float16)xv;
                unsigned int word = (unsigned int)__builtin_bit_cast(unsigned short, xh)
                                  | (off << 16);
                *(unsigned int*)(sxoB + sdst[r]) = word;
            }
        }
        __builtin_amdgcn_wave_barrier();
#pragma unroll
        for (int i = 0; i < CSLOT; ++i) {
            int cell = g + 8*i;
            if (cell < NCELL) {
                uint2 xo = sxo[0][cell];
                const uint4* p0 = (const uint4*)((const char*)sAB16 + (xo.x >> 16) + (d4 << 4));
                const uint4* p1 = (const uint4*)((const char*)sAB16 + (xo.y >> 16) + (d4 << 4));
                uint4 q0 = *p0, q1 = *p1;
                _Float16 x0h = __builtin_bit_cast(_Float16, (unsigned short)(xo.x & 0xffffu));
                _Float16 x1h = __builtin_bit_cast(_Float16, (unsigned short)(xo.y & 0xffffu));
                h2 x0 = {x0h, x0h}, x1 = {x1h, x1h};
                h2 repa = (x0 * __builtin_bit_cast(h2, q0.x) + __builtin_bit_cast(h2, q0.y))
                        * (x1 * __builtin_bit_cast(h2, q1.x) + __builtin_bit_cast(h2, q1.y));
                h2 repb = (x0 * __builtin_bit_cast(h2, q0.z) + __builtin_bit_cast(h2, q0.w))
                        * (x1 * __builtin_bit_cast(h2, q1.z) + __builtin_bit_cast(h2, q1.w));
                wtA[i] = __builtin_bit_cast(unsigned int, (h2)(repa * wv0));
                wtB[i] = __builtin_bit_cast(unsigned int, (h2)(repb * wv1));
                sWt[cell*8 + d4] = make_uint2(wtA[i], wtB[i]);
            }
        }
    }
    __syncthreads();                        // sWt ready for all waves

    if (w != 0) {
#pragma unroll
        for (int i = 0; i < CSLOT; ++i) {
            int cell = g + 8*i;
            if (cell < NCELL) {
                uint2 v = sWt[cell*8 + d4];
                wtA[i] = v.x; wtB[i] = v.y;
            }
        }
    }

    // ======== stripe items (this wave only; no per-item barriers) ========
    for (int j = 0; j < nstripe; ++j) {
        float xc[4];
#pragma unroll
        for (int r = 0; r < 4; ++r) xc[r] = xp[r];

        // prefetch next stripe item (latency hidden behind S+C)
        if (j + 1 < nstripe) {
            const float* row = ctx + (size_t)user_items[b*LLEN + w + NWAVE*(j+1)] * NSCAL;
#pragma unroll
            for (int r = 0; r < 4; ++r) {
                int idx = lane + 64*r;
                if (idx < NSCAL) xp[r] = row[idx];
            }
        }

        // ---- phase S: binary-search segment, pack {fp16(x)|rowoff} ------
#pragma unroll
        for (int r = 0; r < 4; ++r) {
            int idx = lane + 64*r;
            if (idx < NSCAL) {
                float xv = xc[r];
                int base = sc[r]*THRP;
                int pos = 0;
                pos += (sThrS[base + pos + 15] < xv) ? 16 : 0;
                pos += (sThrS[base + pos + 7]  < xv) ? 8  : 0;
                pos += (sThrS[base + pos + 3]  < xv) ? 4  : 0;
                pos += (sThrS[base + pos + 1]  < xv) ? 2  : 0;
                pos += (sThrS[base + pos]      < xv) ? 1  : 0;
                unsigned int off = (unsigned int)((sc[r]*NSEG + pos) << 7);
                _Float16 xh = (_Float16)xv;
                unsigned int word = (unsigned int)__builtin_bit_cast(unsigned short, xh)
                                  | (off << 16);
                *(unsigned int*)(sxoB + sdst[r]) = word;
            }
        }
        __builtin_amdgcn_wave_barrier();

        // ---- phase C: 100 cells x 32 d by this wave alone ----------------
#pragma unroll
        for (int i = 0; i < CSLOT; ++i) {
            int cell = g + 8*i;
            if (cell < NCELL) {
                uint2 xo = sxo[w][cell];
                const uint4* p0 = (const uint4*)((const char*)sAB16 + (xo.x >> 16) + (d4 << 4));
                const uint4* p1 = (const uint4*)((const char*)sAB16 + (xo.y >> 16) + (d4 << 4));
                uint4 q0 = *p0, q1 = *p1;
                _Float16 x0h = __builtin_bit_cast(_Float16, (unsigned short)(xo.x & 0xffffu));
                _Float16 x1h = __builtin_bit_cast(_Float16, (unsigned short)(xo.y & 0xffffu));
                h2 x0 = {x0h, x0h}, x1 = {x1h, x1h};
                h2 repa = (x0 * __builtin_bit_cast(h2, q0.x) + __builtin_bit_cast(h2, q0.y))
                        * (x1 * __builtin_bit_cast(h2, q1.x) + __builtin_bit_cast(h2, q1.y));
                h2 repb = (x0 * __builtin_bit_cast(h2, q0.z) + __builtin_bit_cast(h2, q0.w))
                        * (x1 * __builtin_bit_cast(h2, q1.z) + __builtin_bit_cast(h2, q1.w));
                acc[i] = dot2_acc(repa, __builtin_bit_cast(h2, wtA[i]),
                         dot2_acc(repb, __builtin_bit_cast(h2, wtB[i]), acc[i]));
            }
        }
        __builtin_amdgcn_wave_barrier();
    }

    // ---- epilogue: 8-lane reduce, cross-wave combine, sigmoid -----------
#pragma unroll
    for (int i = 0; i < CSLOT; ++i) {
        int cell = g + 8*i;
        float v = acc[i];
        v += __shfl_xor(v, 1, 64);
        v += __shfl_xor(v, 2, 64);
        v += __shfl_xor(v, 4, 64);
        if (d4 == 0 && cell < NCELL) pRed[w][cell] = v;
    }
    __syncthreads();
    if (tid < NCELL) {
        float p = 0.f;
#pragma unroll
        for (int q = 0; q < NWAVE; ++q) p += pRed[q][tid];
        out[b*NCELL + tid] = 1.f / (1.f + expf(-(p*inv_len + bo)));
    }
}

extern "C" void kernel_launch(void* const* d_in, const int* in_sizes, int n_in,
                              void* d_out, int out_size, void* d_ws, size_t ws_size,
                              hipStream_t stream) {
    const float* ctx   = (const float*)d_in[0];
    const float* W1    = (const float*)d_in[1];
    const float* b1    = (const float*)d_in[2];
    const float* W2    = (const float*)d_in[3];
    const float* b2    = (const float*)d_in[4];
    const float* Wout  = (const float*)d_in[5];
    const float* bout  = (const float*)d_in[6];
    const int* item_idxs  = (const int*)d_in[7];
    const int* user_items = (const int*)d_in[8];
    const int* user_lens  = (const int*)d_in[9];
    float* out = (float*)d_out;
    float* ws  = (float*)d_ws;                 // uses 23,808 B
    int*   order = (int*)(ws + WS_ORDER);

    cnn_setup<<<NSEG + 1, 256, 0, stream>>>(W1, b1, W2, b2, user_lens, ws, order);
    cnn_main<<<BATCH, 512, 0, stream>>>(ctx, ws, Wout, bout,
                                        item_idxs, user_items, user_lens,
                                        order, out);
}